// Round 4
// baseline (292.877 us; speedup 1.0000x reference)
//
#include <hip/hip_runtime.h>
#include <stdint.h>

// Binary conv 3x3, stride 1, pad 1 — XNOR-popcount with zero-padded halo.
//   xp padded: [n][h+1 in 0..57][w+1 in 0..57][8 words] (halo words = 0)
//   out = corr[cfg][o] - 2*sum_{all 9 taps} popc(x ^ w)
//   corr[cfg][o] = 256*nvalid(cfg) + 2*sum_{invalid taps} popc(w_tap)
// (padded tap: popc(0^w)=popc(w), cancelled exactly by corr => branch-free)

#define N_BATCH 32
#define C_IN    256
#define HH      56
#define WW_     56
#define HW      (HH * WW_)   // 3136
#define C_OUT   256
#define WORDS   8            // 256 / 32
#define TAPS    9
#define OBLK    8
#define PH      58
#define PW      58

// ---- pass 1: binarize + bitpack x -> padded xp ----
__global__ __launch_bounds__(256) void pack_x_kernel(const float* __restrict__ x,
                                                     uint32_t* __restrict__ xp) {
    int tid = blockIdx.x * 256 + threadIdx.x;       // 32*3136*8 = 802816
    int s = tid % HW;
    int t = tid / HW;
    int n = t % N_BATCH;
    int word = t / N_BATCH;                          // 0..7
    int h = s / WW_, w = s % WW_;
    const float* px = x + ((size_t)(n * C_IN + word * 32)) * HW + s;
    uint32_t bits = 0;
#pragma unroll
    for (int i = 0; i < 32; ++i) {
        float v = px[(size_t)i * HW];                // coalesced across lanes
        bits |= (v > 0.0f ? 1u : 0u) << i;
    }
    xp[(((size_t)n * PH + (h + 1)) * PW + (w + 1)) * WORDS + word] = bits;
}

// ---- pass 2: binarize + bitpack w -> wp[o][tap][word] ----
__global__ __launch_bounds__(256) void pack_w_kernel(const float* __restrict__ w,
                                                     uint32_t* __restrict__ wp) {
    int tid = blockIdx.x * 256 + threadIdx.x;        // 256*9*8 = 18432
    int o = tid / (TAPS * WORDS);
    int r = tid % (TAPS * WORDS);
    int tap = r / WORDS;
    int j = r % WORDS;
    uint32_t bits = 0;
#pragma unroll
    for (int i = 0; i < 32; ++i) {
        int c = j * 32 + i;
        float v = w[((size_t)(o * C_IN + c)) * TAPS + tap];
        bits |= (v > 0.0f ? 1u : 0u) << i;
    }
    wp[tid] = bits;
}

// ---- pass 2b: border-correction table corrT[cfg][o], cfg = hp*3+wq ----
__global__ void corr_kernel(const uint32_t* __restrict__ wp,
                            uint32_t* __restrict__ corrT) {
    int o = threadIdx.x;                             // 1 block x 256 threads
    int pc[TAPS];
#pragma unroll
    for (int tap = 0; tap < TAPS; ++tap) {
        int c = 0;
#pragma unroll
        for (int j = 0; j < WORDS; ++j)
            c += __popc(wp[((size_t)o * TAPS + tap) * WORDS + j]);
        pc[tap] = c;
    }
#pragma unroll
    for (int hp = 0; hp < 3; ++hp) {
#pragma unroll
        for (int wq = 0; wq < 3; ++wq) {
            int nv = (hp == 1 ? 3 : 2) * (wq == 1 ? 3 : 2);
            int sinv = 0;
#pragma unroll
            for (int kh = -1; kh <= 1; ++kh) {
#pragma unroll
                for (int kw = -1; kw <= 1; ++kw) {
                    bool inv = (kh == -1 && hp == 0) || (kh == 1 && hp == 2) ||
                               (kw == -1 && wq == 0) || (kw == 1 && wq == 2);
                    if (inv) sinv += pc[(kh + 1) * 3 + (kw + 1)];
                }
            }
            corrT[(hp * 3 + wq) * C_OUT + o] = (uint32_t)(256 * nv + 2 * sinv);
        }
    }
}

// ---- pass 3: branch-free xnor-popcount conv ----
__global__ __launch_bounds__(256) void bconv_kernel(const uint32_t* __restrict__ xp,
                                                    const uint32_t* __restrict__ wp,
                                                    const uint32_t* __restrict__ corrT,
                                                    float* __restrict__ out) {
    int s = blockIdx.x * 256 + threadIdx.x;
    if (s >= HW) return;
    int n = blockIdx.z;
    int o_base = blockIdx.y * OBLK;
    int h = s / WW_;
    int w = s % WW_;

    const uint32_t* base = xp + (((size_t)n * PH + (h + 1)) * PW + (w + 1)) * WORDS;

    int acc[OBLK];
#pragma unroll
    for (int o = 0; o < OBLK; ++o) acc[o] = 0;

#pragma unroll
    for (int kh = -1; kh <= 1; ++kh) {
#pragma unroll
        for (int kw = -1; kw <= 1; ++kw) {
            // compile-time tap offset -> folds into load `offset:` immediate
            const uint32_t* px = base + (kh * PW + kw) * WORDS;
            uint4 a = *reinterpret_cast<const uint4*>(px);
            uint4 b = *reinterpret_cast<const uint4*>(px + 4);
            uint32_t xw[8] = {a.x, a.y, a.z, a.w, b.x, b.y, b.z, b.w};
            int tap = (kh + 1) * 3 + (kw + 1);
#pragma unroll
            for (int o = 0; o < OBLK; ++o) {
                const uint32_t* pw = wp + ((size_t)(o_base + o) * TAPS + tap) * WORDS;
#pragma unroll
                for (int j = 0; j < WORDS; ++j) {
                    acc[o] += __popc(xw[j] ^ pw[j]);   // v_xor + v_bcnt(fused add)
                }
            }
        }
    }

    int hp = (h == 0) ? 0 : ((h == HH - 1) ? 2 : 1);
    int wq = (w == 0) ? 0 : ((w == WW_ - 1) ? 2 : 1);
    const uint32_t* ct = corrT + (hp * 3 + wq) * C_OUT + o_base;

#pragma unroll
    for (int o = 0; o < OBLK; ++o) {
        out[((size_t)(n * C_OUT + o_base + o)) * HW + s] =
            (float)((int)ct[o] - 2 * acc[o]);
    }
}

extern "C" void kernel_launch(void* const* d_in, const int* in_sizes, int n_in,
                              void* d_out, int out_size, void* d_ws, size_t ws_size,
                              hipStream_t stream) {
    const float* x = (const float*)d_in[0];
    const float* w = (const float*)d_in[1];
    float* out = (float*)d_out;

    uint32_t* xp    = (uint32_t*)d_ws;                       // 32*58*58*8 = 861184 u32
    uint32_t* wp    = xp + (size_t)N_BATCH * PH * PW * WORDS; // 18432 u32
    uint32_t* corrT = wp + (size_t)C_OUT * TAPS * WORDS;      // 2304 u32

    // zero padded buffer (halo must be 0; ws is re-poisoned to 0xAA every call)
    hipMemsetAsync(xp, 0, (size_t)N_BATCH * PH * PW * WORDS * sizeof(uint32_t), stream);

    pack_x_kernel<<<dim3(HW * N_BATCH * WORDS / 256), 256, 0, stream>>>(x, xp);
    pack_w_kernel<<<dim3(C_OUT * TAPS * WORDS / 256), 256, 0, stream>>>(w, wp);
    corr_kernel<<<dim3(1), 256, 0, stream>>>(wp, corrT);

    dim3 grid((HW + 255) / 256, C_OUT / OBLK, N_BATCH);
    bconv_kernel<<<grid, 256, 0, stream>>>(xp, wp, corrT, out);
}